// Round 1
// baseline (5650.459 us; speedup 1.0000x reference)
//
#include <hip/hip_runtime.h>
#include <stdint.h>

typedef __bf16 bf16;
typedef __bf16 bf16x4 __attribute__((ext_vector_type(4)));
typedef __bf16 bf16x8 __attribute__((ext_vector_type(8)));
typedef float f32x4 __attribute__((ext_vector_type(4)));

#define NB_REC 256   // recurrence grid blocks (must all be co-resident; 256 CUs)

__device__ __forceinline__ float fast_tanh(float x) {
  x = fminf(fmaxf(x, -15.f), 15.f);
  float u = __expf(2.f * x);
  return (u - 1.f) / (u + 1.f);
}
__device__ __forceinline__ float fast_sigmoid(float x) {
  return 1.f / (1.f + __expf(-x));
}

// ---------------- prep kernels ----------------
__global__ __launch_bounds__(256) void f2bf_k(const float* __restrict__ s,
                                              bf16* __restrict__ d, long n) {
  long i = ((long)blockIdx.x * 256 + threadIdx.x) * 4;
  if (i >= n) return;
  float4 v = *(const float4*)(s + i);
  bf16x4 o = {(bf16)v.x, (bf16)v.y, (bf16)v.z, (bf16)v.w};
  *(bf16x4*)(d + i) = o;
}

__global__ __launch_bounds__(256) void copyf_k(const float* __restrict__ s,
                                               float* __restrict__ d, long n) {
  long i = ((long)blockIdx.x * 256 + threadIdx.x) * 4;
  if (i >= n) return;
  *(float4*)(d + i) = *(const float4*)(s + i);
}

// split W_ih [1536,1024] into x-half [1536,512] and context-half [1536,512] (bf16)
__global__ __launch_bounds__(256) void split_wih_k(const float* __restrict__ W,
                                                   bf16* __restrict__ X,
                                                   bf16* __restrict__ Cc) {
  long i = ((long)blockIdx.x * 256 + threadIdx.x) * 4;  // over 1536*512
  if (i >= (long)1536 * 512) return;
  long j = i >> 9, k = i & 511;
  float4 a = *(const float4*)(W + j * 1024 + k);
  float4 b = *(const float4*)(W + j * 1024 + 512 + k);
  bf16x4 oa = {(bf16)a.x, (bf16)a.y, (bf16)a.z, (bf16)a.w};
  bf16x4 ob = {(bf16)b.x, (bf16)b.y, (bf16)b.z, (bf16)b.w};
  *(bf16x4*)(X + i) = oa;
  *(bf16x4*)(Cc + i) = ob;
}

// xemb[m = b*64+t, :] = bf16(emb[tok(b,t)]), tok = t==0 ? SOS(0) : target[b,t-1]
__global__ __launch_bounds__(256) void embed_k(const int* __restrict__ tgt,
                                               const float* __restrict__ emb,
                                               bf16* __restrict__ xe) {
  long i = ((long)blockIdx.x * 256 + threadIdx.x) * 4;  // over 2048*512
  if (i >= (long)2048 * 512) return;
  long m = i >> 9, k = i & 511;
  int b = (int)(m >> 6), t = (int)(m & 63);
  int tok = (t == 0) ? 0 : tgt[b * 64 + t - 1];
  float4 v = *(const float4*)(emb + (long)tok * 512 + k);
  bf16x4 o = {(bf16)v.x, (bf16)v.y, (bf16)v.z, (bf16)v.w};
  *(bf16x4*)(xe + i) = o;
}

// ---------------- bf16 MFMA GEMM:  C[2048,N] = A[2048,512] * B[N,512]^T (+bias[n]) ----------------
// 128x128 tile, BK=32, 4 waves, each wave 4x4 tiles of 16x16x32. Register-staged LDS.
__global__ __launch_bounds__(256) void gemm_bt(const bf16* __restrict__ A,
                                               const bf16* __restrict__ Bm,
                                               const float* __restrict__ bias,
                                               float* __restrict__ C, int N) {
  __shared__ bf16 As[128 * 32];
  __shared__ bf16 Bs[128 * 32];
  const int tid = threadIdx.x;
  const int bx = blockIdx.x;
  const int bm = bx & 15;       // M/128 = 16
  const int bn = bx >> 4;
  const int lane = tid & 63;
  const int w = tid >> 6;
  const int l16 = lane & 15, q4 = lane >> 4;
  const int wm = (w & 1) * 64, wn = (w >> 1) * 64;
  const long m0 = (long)bm * 128;
  const long n0 = (long)bn * 128;
  const int r0 = tid >> 2;            // 0..63
  const int kp8 = (tid & 3) * 8;      // k-part within 32 (element units)

  f32x4 acc[4][4] = {};
  for (int kk = 0; kk < 512; kk += 32) {
    __syncthreads();
    {
      bf16x8 va0 = *(const bf16x8*)(A + (m0 + r0) * 512 + kk + kp8);
      bf16x8 va1 = *(const bf16x8*)(A + (m0 + 64 + r0) * 512 + kk + kp8);
      bf16x8 vb0 = *(const bf16x8*)(Bm + (n0 + r0) * 512 + kk + kp8);
      bf16x8 vb1 = *(const bf16x8*)(Bm + (n0 + 64 + r0) * 512 + kk + kp8);
      *(bf16x8*)&As[r0 * 32 + kp8] = va0;
      *(bf16x8*)&As[(64 + r0) * 32 + kp8] = va1;
      *(bf16x8*)&Bs[r0 * 32 + kp8] = vb0;
      *(bf16x8*)&Bs[(64 + r0) * 32 + kp8] = vb1;
    }
    __syncthreads();
    bf16x8 af[4], bfr[4];
#pragma unroll
    for (int i = 0; i < 4; ++i)
      af[i] = *(const bf16x8*)&As[(wm + i * 16 + l16) * 32 + q4 * 8];
#pragma unroll
    for (int j = 0; j < 4; ++j)
      bfr[j] = *(const bf16x8*)&Bs[(wn + j * 16 + l16) * 32 + q4 * 8];
#pragma unroll
    for (int i = 0; i < 4; ++i)
#pragma unroll
      for (int j = 0; j < 4; ++j)
        acc[i][j] = __builtin_amdgcn_mfma_f32_16x16x32_bf16(af[i], bfr[j], acc[i][j], 0, 0, 0);
  }
  // epilogue: D row = q4*4+reg, col = l16  (verified C/D layout)
#pragma unroll
  for (int i = 0; i < 4; ++i) {
    const long rbase = m0 + wm + i * 16 + q4 * 4;
#pragma unroll
    for (int j = 0; j < 4; ++j) {
      const long col = n0 + wn + j * 16 + l16;
      const float bv = bias ? bias[col] : 0.f;
      f32x4 a = acc[i][j];
      C[(rbase + 0) * N + col] = a[0] + bv;
      C[(rbase + 1) * N + col] = a[1] + bv;
      C[(rbase + 2) * N + col] = a[2] + bv;
      C[(rbase + 3) * N + col] = a[3] + bv;
    }
  }
}

// ---------------- grid barrier (agent scope, sense via generation counter) ----------------
__device__ __forceinline__ void grid_bar(unsigned* cnt, unsigned* gen, unsigned nb) {
  __syncthreads();
  if (threadIdx.x == 0) {
    __threadfence();  // release my block's writes (agent scope)
    unsigned g = __hip_atomic_load(gen, __ATOMIC_RELAXED, __HIP_MEMORY_SCOPE_AGENT);
    unsigned a = __hip_atomic_fetch_add(cnt, 1u, __ATOMIC_ACQ_REL, __HIP_MEMORY_SCOPE_AGENT);
    if (a == nb - 1u) {
      __hip_atomic_store(cnt, 0u, __ATOMIC_RELAXED, __HIP_MEMORY_SCOPE_AGENT);
      __hip_atomic_store(gen, g + 1u, __ATOMIC_RELEASE, __HIP_MEMORY_SCOPE_AGENT);
    } else {
      while (__hip_atomic_load(gen, __ATOMIC_ACQUIRE, __HIP_MEMORY_SCOPE_AGENT) == g) {
        __builtin_amdgcn_s_sleep(1);
      }
    }
    __threadfence();  // acquire remote writes
  }
  __syncthreads();
}

// ---------------- persistent recurrence kernel ----------------
// grid = 256 blocks x 256 threads. Per step t:
//  P1 (blocks 0..127, wave 0): QG[32,2048] = h @ [Wa;W_hh]^T (+ba|+b_hh) via MFMA, 16 cols/block
//  barrier
//  P2 (all blocks; b = g&31, p = g>>5): scores/softmax (redundant per batch),
//     gi_ctx slice via ep, GRU gates for j in [p*64,(p+1)*64), write h/hist/attn/hT
//  barrier
__global__ __launch_bounds__(256) void recurrence_k(
    const bf16* __restrict__ Wc,      // [2048,512] = [Wa;W_hh] bf16
    const float* __restrict__ ba,     // [512]
    const float* __restrict__ bhh,    // [1536]
    const bf16* __restrict__ h0b,     // [32,512]
    bf16* __restrict__ histb,         // [2048,512]  m=b*64+t
    float* __restrict__ QG,           // [32,2048]
    const float* __restrict__ kp,     // [2048,512]  m=b*64+s  (keys_proj)
    const float* __restrict__ va,     // [512]
    const float* __restrict__ gix,    // [2048,1536] m=b*64+t  (x-part gates, incl b_ih)
    const float* __restrict__ ep,     // [2048,1536] m=b*64+s  (enc @ W_ihc^T)
    float* __restrict__ h32,          // [32,512] running hidden fp32 (pre-init h0)
    float* __restrict__ outhT,        // [32,512]
    float* __restrict__ outattn,      // [2048,64]
    unsigned* __restrict__ bar) {
  const int g = blockIdx.x;
  const int tid = threadIdx.x;
  const int b = g & 31;   // keeps all 8 blocks of batch b on XCD b%8
  const int p = g >> 5;   // 0..7
  __shared__ float va_s[512], q_s[512], sc_s[64], w_s[64], gi_s[192], gh_s[192];
  va_s[tid] = va[tid];
  va_s[256 + tid] = va[256 + tid];
  unsigned* cnt = bar;
  unsigned* gen = bar + 1;

  for (int t = 0; t < 64; ++t) {
    // ---- P1: QG = h @ Wc^T (MFMA, wave 0 of blocks 0..127) ----
    if (g < 128 && tid < 64) {
      const int l16 = tid & 15, q4 = tid >> 4;
      const int n0 = g * 16;
      const bf16* hb;
      long strd;
      if (t == 0) { hb = h0b; strd = 512; }
      else        { hb = histb + (long)(t - 1) * 512; strd = (long)64 * 512; }
      const bf16* a0p = hb + (long)l16 * strd + q4 * 8;
      const bf16* a1p = hb + (long)(16 + l16) * strd + q4 * 8;
      const bf16* bp = Wc + (long)(n0 + l16) * 512 + q4 * 8;
      f32x4 acc0 = {}, acc1 = {};
#pragma unroll
      for (int kk = 0; kk < 512; kk += 32) {
        bf16x8 bb = *(const bf16x8*)(bp + kk);
        bf16x8 a0 = *(const bf16x8*)(a0p + kk);
        bf16x8 a1 = *(const bf16x8*)(a1p + kk);
        acc0 = __builtin_amdgcn_mfma_f32_16x16x32_bf16(a0, bb, acc0, 0, 0, 0);
        acc1 = __builtin_amdgcn_mfma_f32_16x16x32_bf16(a1, bb, acc1, 0, 0, 0);
      }
      const int col = n0 + l16;
      const float badd = (col < 512) ? ba[col] : bhh[col - 512];
#pragma unroll
      for (int r = 0; r < 4; ++r) {
        QG[(q4 * 4 + r) * 2048 + col] = acc0[r] + badd;
        QG[(16 + q4 * 4 + r) * 2048 + col] = acc1[r] + badd;
      }
    }
    grid_bar(cnt, gen, NB_REC);

    // ---- P2 ----
    q_s[tid] = QG[b * 2048 + tid];
    q_s[256 + tid] = QG[b * 2048 + 256 + tid];
    __syncthreads();
    {  // scores: s = tid>>2, quarter of K per thread
      const int s = tid >> 2, kq = tid & 3;
      const float* kpr = kp + (long)(b * 64 + s) * 512 + kq * 128;
      const float* qr = q_s + kq * 128;
      const float* vr = va_s + kq * 128;
      float acc = 0.f;
#pragma unroll 8
      for (int k = 0; k < 128; k += 4) {
        float4 kv = *(const float4*)(kpr + k);
        acc += vr[k + 0] * fast_tanh(qr[k + 0] + kv.x);
        acc += vr[k + 1] * fast_tanh(qr[k + 1] + kv.y);
        acc += vr[k + 2] * fast_tanh(qr[k + 2] + kv.z);
        acc += vr[k + 3] * fast_tanh(qr[k + 3] + kv.w);
      }
      acc += __shfl_xor(acc, 1);
      acc += __shfl_xor(acc, 2);
      if (kq == 0) sc_s[s] = acc;
    }
    __syncthreads();
    if (tid < 64) {  // softmax over 64 scores (bounded; no max-shift needed)
      float e = __expf(sc_s[tid]);
      float sum = e;
#pragma unroll
      for (int d = 1; d < 64; d <<= 1) sum += __shfl_xor(sum, d);
      float wv = e / sum;
      w_s[tid] = wv;
      if (p == 0) outattn[(long)(b * 64 + t) * 64 + tid] = wv;
    }
    __syncthreads();
    if (tid < 192) {  // gi slice: cols {j, 512+j, 1024+j} for j in [p*64,(p+1)*64)
      const int part = tid >> 6, jj = tid & 63;
      const int col = part * 512 + p * 64 + jj;
      const float* er = ep + (long)(b * 64) * 1536 + col;
      float acc = 0.f;
#pragma unroll 8
      for (int s2 = 0; s2 < 64; ++s2) acc += w_s[s2] * er[(long)s2 * 1536];
      gi_s[tid] = acc + gix[(long)(b * 64 + t) * 1536 + col];
      gh_s[tid] = QG[b * 2048 + 512 + col];
    }
    __syncthreads();
    if (tid < 64) {  // GRU gates + hidden update
      const int j = p * 64 + tid;
      float rr = fast_sigmoid(gi_s[tid] + gh_s[tid]);
      float zz = fast_sigmoid(gi_s[64 + tid] + gh_s[64 + tid]);
      float nn = fast_tanh(gi_s[128 + tid] + rr * gh_s[128 + tid]);
      float hp = h32[b * 512 + j];
      float hn = (1.f - zz) * nn + zz * hp;
      h32[b * 512 + j] = hn;
      histb[(long)(b * 64 + t) * 512 + j] = (bf16)hn;
      if (t == 63) outhT[b * 512 + j] = hn;
    }
    grid_bar(cnt, gen, NB_REC);
  }
}

// ---------------- in-place log-softmax over V=32000 per row ----------------
__global__ __launch_bounds__(256) void logsm_k(float* __restrict__ C) {
  const long row = blockIdx.x;
  float* x = C + row * 32000L;
  const int tid = threadIdx.x;
  __shared__ float red[4];
  float s = 0.f;
  for (long i = (long)tid * 4; i < 32000; i += 1024) {
    float4 v = *(const float4*)(x + i);
    s += __expf(v.x);
    s += __expf(v.y);
    s += __expf(v.z);
    s += __expf(v.w);
  }
#pragma unroll
  for (int d = 1; d < 64; d <<= 1) s += __shfl_xor(s, d);
  if ((tid & 63) == 0) red[tid >> 6] = s;
  __syncthreads();
  const float lse = __logf(red[0] + red[1] + red[2] + red[3]);
  for (long i = (long)tid * 4; i < 32000; i += 1024) {
    float4 v = *(const float4*)(x + i);
    v.x -= lse; v.y -= lse; v.z -= lse; v.w -= lse;
    *(float4*)(x + i) = v;
  }
}

// ---------------- launcher ----------------
extern "C" void kernel_launch(void* const* d_in, const int* in_sizes, int n_in,
                              void* d_out, int out_size, void* d_ws, size_t ws_size,
                              hipStream_t stream) {
  const float* enc  = (const float*)d_in[0];   // [32,64,512]
  const float* ehid = (const float*)d_in[1];   // [1,32,512]
  const int* tgt    = (const int*)d_in[2];     // [32,64]
  const float* emb  = (const float*)d_in[3];   // [32000,512]
  const float* Wa   = (const float*)d_in[4];   // [512,512]
  const float* ba   = (const float*)d_in[5];   // [512]
  const float* Ua   = (const float*)d_in[6];   // [512,512]
  const float* bu   = (const float*)d_in[7];   // [512]
  const float* Va   = (const float*)d_in[8];   // [1,512]
  // d_in[9] = bv: softmax shift-invariant, unused
  const float* Wih  = (const float*)d_in[10];  // [1536,1024]
  const float* bih  = (const float*)d_in[11];  // [1536]
  const float* Whh  = (const float*)d_in[12];  // [1536,512]
  const float* bhh  = (const float*)d_in[13];  // [1536]
  const float* Wout = (const float*)d_in[14];  // [32000,512]
  const float* bout = (const float*)d_in[15];  // [32000]

  char* ws = (char*)d_ws;
  size_t off = 0;
  auto alloc = [&](size_t bytes) {
    void* pp = ws + off;
    off += (bytes + 255) & ~(size_t)255;
    return pp;
  };
  unsigned* bar  = (unsigned*)alloc(256);
  bf16* enc_bf   = (bf16*)alloc((long)2048 * 512 * 2);
  bf16* Wc_bf    = (bf16*)alloc((long)2048 * 512 * 2);    // [Wa;W_hh]
  bf16* Ua_bf    = (bf16*)alloc((long)512 * 512 * 2);
  bf16* Wihx_bf  = (bf16*)alloc((long)1536 * 512 * 2);
  bf16* Wihc_bf  = (bf16*)alloc((long)1536 * 512 * 2);
  bf16* xemb_bf  = (bf16*)alloc((long)2048 * 512 * 2);
  bf16* h0_bf    = (bf16*)alloc((long)32 * 512 * 2);
  bf16* histb    = (bf16*)alloc((long)2048 * 512 * 2);
  bf16* Wout_bf  = (bf16*)alloc((long)32000 * 512 * 2);
  float* kp      = (float*)alloc((long)2048 * 512 * 4);
  float* gix     = (float*)alloc((long)2048 * 1536 * 4);
  float* ep      = (float*)alloc((long)2048 * 1536 * 4);
  float* QG      = (float*)alloc((long)32 * 2048 * 4);
  float* h32     = (float*)alloc((long)32 * 512 * 4);
  (void)ws_size; (void)in_sizes; (void)n_in; (void)out_size;

  float* out0   = (float*)d_out;           // [32,64,32000] log-probs
  float* outhT  = out0 + (long)2048 * 32000;  // [1,32,512]
  float* outatt = outhT + (long)32 * 512;     // [32,64,64]

  hipMemsetAsync(bar, 0, 256, stream);

  dim3 blk(256);
  // conversions / packing
  f2bf_k<<<dim3(1024), blk, 0, stream>>>(enc, enc_bf, (long)2048 * 512);
  f2bf_k<<<dim3(256), blk, 0, stream>>>(Ua, Ua_bf, (long)512 * 512);
  f2bf_k<<<dim3(16000), blk, 0, stream>>>(Wout, Wout_bf, (long)32000 * 512);
  f2bf_k<<<dim3(16), blk, 0, stream>>>(ehid, h0_bf, (long)32 * 512);
  f2bf_k<<<dim3(256), blk, 0, stream>>>(Wa, Wc_bf, (long)512 * 512);
  f2bf_k<<<dim3(768), blk, 0, stream>>>(Whh, Wc_bf + (long)512 * 512, (long)1536 * 512);
  split_wih_k<<<dim3(768), blk, 0, stream>>>(Wih, Wihx_bf, Wihc_bf);
  embed_k<<<dim3(1024), blk, 0, stream>>>(tgt, emb, xemb_bf);
  copyf_k<<<dim3(16), blk, 0, stream>>>(ehid, h32, (long)32 * 512);

  // step-invariant GEMMs
  gemm_bt<<<dim3(16 * 4), blk, 0, stream>>>(enc_bf, Ua_bf, bu, kp, 512);         // keys_proj
  gemm_bt<<<dim3(16 * 12), blk, 0, stream>>>(xemb_bf, Wihx_bf, bih, gix, 1536);  // gi_x (+b_ih)
  gemm_bt<<<dim3(16 * 12), blk, 0, stream>>>(enc_bf, Wihc_bf, (const float*)nullptr, ep, 1536);

  // sequential decode (persistent, grid-barriered)
  recurrence_k<<<dim3(NB_REC), blk, 0, stream>>>(Wc_bf, ba, bhh, h0_bf, histb, QG,
                                                 kp, Va, gix, ep, h32, outhT, outatt, bar);

  // logits = h_hist @ Wout^T + bout, then in-place log-softmax
  gemm_bt<<<dim3(16 * 250), blk, 0, stream>>>(histb, Wout_bf, bout, out0, 32000);
  logsm_k<<<dim3(2048), blk, 0, stream>>>(out0);
}

// Round 2
// 2027.722 us; speedup vs baseline: 2.7866x; 2.7866x over previous
//
#include <hip/hip_runtime.h>
#include <stdint.h>

typedef __bf16 bf16;
typedef __bf16 bf16x4 __attribute__((ext_vector_type(4)));
typedef __bf16 bf16x8 __attribute__((ext_vector_type(8)));
typedef float f32x4 __attribute__((ext_vector_type(4)));

#define NB_REC 256   // recurrence grid blocks (must all be co-resident; 256 CUs)

__device__ __forceinline__ float fast_tanh(float x) {
  x = fminf(fmaxf(x, -15.f), 15.f);
  float u = __expf(2.f * x);
  return (u - 1.f) / (u + 1.f);
}
__device__ __forceinline__ float fast_sigmoid(float x) {
  return 1.f / (1.f + __expf(-x));
}

// ---------------- prep kernels ----------------
__global__ __launch_bounds__(256) void f2bf_k(const float* __restrict__ s,
                                              bf16* __restrict__ d, long n) {
  long i = ((long)blockIdx.x * 256 + threadIdx.x) * 4;
  if (i >= n) return;
  float4 v = *(const float4*)(s + i);
  bf16x4 o = {(bf16)v.x, (bf16)v.y, (bf16)v.z, (bf16)v.w};
  *(bf16x4*)(d + i) = o;
}

// split W_ih [1536,1024] into x-half [1536,512] and context-half [1536,512] (bf16)
__global__ __launch_bounds__(256) void split_wih_k(const float* __restrict__ W,
                                                   bf16* __restrict__ X,
                                                   bf16* __restrict__ Cc) {
  long i = ((long)blockIdx.x * 256 + threadIdx.x) * 4;  // over 1536*512
  if (i >= (long)1536 * 512) return;
  long j = i >> 9, k = i & 511;
  float4 a = *(const float4*)(W + j * 1024 + k);
  float4 b = *(const float4*)(W + j * 1024 + 512 + k);
  bf16x4 oa = {(bf16)a.x, (bf16)a.y, (bf16)a.z, (bf16)a.w};
  bf16x4 ob = {(bf16)b.x, (bf16)b.y, (bf16)b.z, (bf16)b.w};
  *(bf16x4*)(X + i) = oa;
  *(bf16x4*)(Cc + i) = ob;
}

// xemb[m = b*64+t, :] = bf16(emb[tok(b,t)]), tok = t==0 ? SOS(0) : target[b,t-1]
__global__ __launch_bounds__(256) void embed_k(const int* __restrict__ tgt,
                                               const float* __restrict__ emb,
                                               bf16* __restrict__ xe) {
  long i = ((long)blockIdx.x * 256 + threadIdx.x) * 4;  // over 2048*512
  if (i >= (long)2048 * 512) return;
  long m = i >> 9, k = i & 511;
  int b = (int)(m >> 6), t = (int)(m & 63);
  int tok = (t == 0) ? 0 : tgt[b * 64 + t - 1];
  float4 v = *(const float4*)(emb + (long)tok * 512 + k);
  bf16x4 o = {(bf16)v.x, (bf16)v.y, (bf16)v.z, (bf16)v.w};
  *(bf16x4*)(xe + i) = o;
}

// kpT[b][k][s] = kp[b*64+s][k]   (for coalesced lane=s reads in scores)
__global__ __launch_bounds__(256) void kpt_k(const float* __restrict__ kp,
                                             float* __restrict__ kpT) {
  long i = (long)blockIdx.x * 256 + threadIdx.x;  // over 32*512*64 = 1048576
  if (i >= (long)32 * 512 * 64) return;
  int b = (int)(i >> 15);
  int r = (int)(i & 32767);
  int k = r >> 6, s = r & 63;
  kpT[i] = kp[((long)b * 64 + s) * 512 + k];
}

// ---------------- bf16 MFMA GEMM:  C[2048,N] = A[2048,512] * B[N,512]^T (+bias[n]) ----------------
__global__ __launch_bounds__(256) void gemm_bt(const bf16* __restrict__ A,
                                               const bf16* __restrict__ Bm,
                                               const float* __restrict__ bias,
                                               float* __restrict__ C, int N) {
  __shared__ bf16 As[128 * 32];
  __shared__ bf16 Bs[128 * 32];
  const int tid = threadIdx.x;
  const int bx = blockIdx.x;
  const int bm = bx & 15;       // M/128 = 16
  const int bn = bx >> 4;
  const int lane = tid & 63;
  const int w = tid >> 6;
  const int l16 = lane & 15, q4 = lane >> 4;
  const int wm = (w & 1) * 64, wn = (w >> 1) * 64;
  const long m0 = (long)bm * 128;
  const long n0 = (long)bn * 128;
  const int r0 = tid >> 2;            // 0..63
  const int kp8 = (tid & 3) * 8;      // k-part within 32 (element units)

  f32x4 acc[4][4] = {};
  for (int kk = 0; kk < 512; kk += 32) {
    __syncthreads();
    {
      bf16x8 va0 = *(const bf16x8*)(A + (m0 + r0) * 512 + kk + kp8);
      bf16x8 va1 = *(const bf16x8*)(A + (m0 + 64 + r0) * 512 + kk + kp8);
      bf16x8 vb0 = *(const bf16x8*)(Bm + (n0 + r0) * 512 + kk + kp8);
      bf16x8 vb1 = *(const bf16x8*)(Bm + (n0 + 64 + r0) * 512 + kk + kp8);
      *(bf16x8*)&As[r0 * 32 + kp8] = va0;
      *(bf16x8*)&As[(64 + r0) * 32 + kp8] = va1;
      *(bf16x8*)&Bs[r0 * 32 + kp8] = vb0;
      *(bf16x8*)&Bs[(64 + r0) * 32 + kp8] = vb1;
    }
    __syncthreads();
    bf16x8 af[4], bfr[4];
#pragma unroll
    for (int i = 0; i < 4; ++i)
      af[i] = *(const bf16x8*)&As[(wm + i * 16 + l16) * 32 + q4 * 8];
#pragma unroll
    for (int j = 0; j < 4; ++j)
      bfr[j] = *(const bf16x8*)&Bs[(wn + j * 16 + l16) * 32 + q4 * 8];
#pragma unroll
    for (int i = 0; i < 4; ++i)
#pragma unroll
      for (int j = 0; j < 4; ++j)
        acc[i][j] = __builtin_amdgcn_mfma_f32_16x16x32_bf16(af[i], bfr[j], acc[i][j], 0, 0, 0);
  }
#pragma unroll
  for (int i = 0; i < 4; ++i) {
    const long rbase = m0 + wm + i * 16 + q4 * 4;
#pragma unroll
    for (int j = 0; j < 4; ++j) {
      const long col = n0 + wn + j * 16 + l16;
      const float bv = bias ? bias[col] : 0.f;
      f32x4 a = acc[i][j];
      C[(rbase + 0) * N + col] = a[0] + bv;
      C[(rbase + 1) * N + col] = a[1] + bv;
      C[(rbase + 2) * N + col] = a[2] + bv;
      C[(rbase + 3) * N + col] = a[3] + bv;
    }
  }
}

// ---------------- lightweight hierarchical grid barrier ----------------
// bar[grp*16] : per-group monotone arrival counters (8 groups x 32 blocks)
// bar[128]    : root counter (one bump per group per epoch)
// No fences, no L2 wb/inv. All cross-block data uses relaxed AGENT-scope
// atomics (sc-bit coherent at Infinity Cache), ordered by s_waitcnt(0).
__device__ __forceinline__ void gbar(unsigned* bar, int g, unsigned epoch) {
  __syncthreads();
  if (threadIdx.x == 0) {
    __builtin_amdgcn_s_waitcnt(0);  // my coherent stores are globally visible
    __atomic_signal_fence(__ATOMIC_SEQ_CST);
    unsigned a = __hip_atomic_fetch_add(&bar[(g >> 5) * 16], 1u,
                                        __ATOMIC_RELAXED, __HIP_MEMORY_SCOPE_AGENT);
    if ((a & 31u) == 31u)
      __hip_atomic_fetch_add(&bar[128], 1u, __ATOMIC_RELAXED, __HIP_MEMORY_SCOPE_AGENT);
    while (__hip_atomic_load(&bar[128], __ATOMIC_RELAXED, __HIP_MEMORY_SCOPE_AGENT) <
           epoch * 8u)
      __builtin_amdgcn_s_sleep(2);
    __atomic_signal_fence(__ATOMIC_SEQ_CST);
  }
  __syncthreads();
}

__device__ __forceinline__ unsigned long long coh_load_u64(const unsigned long long* p) {
  return __hip_atomic_load(p, __ATOMIC_RELAXED, __HIP_MEMORY_SCOPE_AGENT);
}
__device__ __forceinline__ float coh_load_f32(const float* p) {
  return __hip_atomic_load(p, __ATOMIC_RELAXED, __HIP_MEMORY_SCOPE_AGENT);
}

// ---------------- persistent recurrence kernel ----------------
// 256 blocks x 256 threads. b = g&31 (all 8 blocks of batch b land on XCD b%8),
// p = g>>5. Per step:
//  P1 (blocks 0..127, wave 0): QG[32,2048] = h @ [Wa;W_hh]^T + bias  (MFMA)
//  gbar
//  P2 (all blocks): scores (lane=s, coalesced kpT) -> softmax -> gi ctx slice
//                   -> GRU gates for j in [p*64,(p+1)*64) -> publish h
//  gbar
__global__ __launch_bounds__(256) void recurrence_k(
    const bf16* __restrict__ Wc,      // [2048,512] = [Wa;W_hh] bf16
    const float* __restrict__ ba,     // [512]
    const float* __restrict__ bhh,    // [1536]
    const float* __restrict__ ehid,   // [32,512] h0 fp32
    unsigned long long* __restrict__ h_bfg,  // [32*128] packed bf16 (coherent)
    bf16* __restrict__ histb,         // [2048,512] ordinary (next-kernel GEMM)
    float* __restrict__ QG,           // [32,2048] (coherent)
    const float* __restrict__ kpT,    // [32,512,64]
    const float* __restrict__ va,     // [512]
    const float* __restrict__ gix,    // [2048,1536]
    const float* __restrict__ ep,     // [2048,1536]
    float* __restrict__ outhT,        // [32,512]
    float* __restrict__ outattn,      // [2048,64]
    unsigned* __restrict__ bar) {
  const int g = blockIdx.x;
  const int tid = threadIdx.x;
  const int b = g & 31;
  const int p = g >> 5;
  __shared__ float va_s[512], q_s[512], part_s[256], w_s[64];
  __shared__ float gi_s[192], gh_s[192], h_loc[64];
  unsigned epoch = 0;

  va_s[tid] = va[tid];
  va_s[256 + tid] = va[256 + tid];
  if (tid < 64) h_loc[tid] = ehid[b * 512 + p * 64 + tid];
  // publish h0 as packed bf16 (blocks 0..31, one per batch)
  if (g < 32 && tid < 128) {
    const float* hr = ehid + g * 512 + tid * 4;
    union { bf16 h[4]; unsigned long long u; } cv;
    cv.h[0] = (bf16)hr[0]; cv.h[1] = (bf16)hr[1];
    cv.h[2] = (bf16)hr[2]; cv.h[3] = (bf16)hr[3];
    __hip_atomic_store(&h_bfg[g * 128 + tid], cv.u, __ATOMIC_RELAXED,
                       __HIP_MEMORY_SCOPE_AGENT);
  }
  ++epoch;
  gbar(bar, g, epoch);

  for (int t = 0; t < 64; ++t) {
    // ---- P1: QG = h @ Wc^T + bias (MFMA, wave 0 of blocks 0..127) ----
    if (g < 128 && tid < 64) {
      const int l16 = tid & 15, q4 = tid >> 4;
      const int n0 = g * 16;
      const bf16* bp = Wc + (long)(n0 + l16) * 512 + q4 * 8;
      const unsigned long long* a0p = h_bfg + l16 * 128 + q4 * 2;
      const unsigned long long* a1p = h_bfg + (16 + l16) * 128 + q4 * 2;
      f32x4 acc0 = {}, acc1 = {};
#pragma unroll
      for (int it = 0; it < 16; ++it) {
        union { unsigned long long u[2]; bf16x8 v; } A0, A1;
        A0.u[0] = coh_load_u64(a0p + it * 8 + 0);
        A0.u[1] = coh_load_u64(a0p + it * 8 + 1);
        A1.u[0] = coh_load_u64(a1p + it * 8 + 0);
        A1.u[1] = coh_load_u64(a1p + it * 8 + 1);
        bf16x8 bb = *(const bf16x8*)(bp + it * 32);
        acc0 = __builtin_amdgcn_mfma_f32_16x16x32_bf16(A0.v, bb, acc0, 0, 0, 0);
        acc1 = __builtin_amdgcn_mfma_f32_16x16x32_bf16(A1.v, bb, acc1, 0, 0, 0);
      }
      const int col = n0 + l16;
      const float badd = (col < 512) ? ba[col] : bhh[col - 512];
#pragma unroll
      for (int r = 0; r < 4; ++r) {
        __hip_atomic_store(&QG[(q4 * 4 + r) * 2048 + col], acc0[r] + badd,
                           __ATOMIC_RELAXED, __HIP_MEMORY_SCOPE_AGENT);
        __hip_atomic_store(&QG[(16 + q4 * 4 + r) * 2048 + col], acc1[r] + badd,
                           __ATOMIC_RELAXED, __HIP_MEMORY_SCOPE_AGENT);
      }
    }
    ++epoch;
    gbar(bar, g, epoch);

    // ---- P2a: pull q (512) and my gh slice (192) from QG ----
    q_s[tid] = coh_load_f32(&QG[b * 2048 + tid]);
    q_s[256 + tid] = coh_load_f32(&QG[b * 2048 + 256 + tid]);
    if (tid < 192) {
      const int part = tid >> 6, jj = tid & 63;
      gh_s[tid] = coh_load_f32(&QG[b * 2048 + 512 + part * 512 + p * 64 + jj]);
    }
    __syncthreads();

    // ---- P2b: scores. wave w covers k in [w*128,(w+1)*128), lane = s ----
    {
      const int w = tid >> 6, l = tid & 63;
      const float* kprow = kpT + ((long)b * 512 + w * 128) * 64 + l;
      float acc = 0.f;
#pragma unroll 4
      for (int k = 0; k < 128; ++k)
        acc += va_s[w * 128 + k] * fast_tanh(q_s[w * 128 + k] + kprow[(long)k * 64]);
      part_s[w * 64 + l] = acc;
    }
    __syncthreads();
    if (tid < 64) {  // softmax over 64 scores (bounded; no max-shift needed)
      float sc = part_s[tid] + part_s[64 + tid] + part_s[128 + tid] + part_s[192 + tid];
      float e = __expf(sc);
      float sum = e;
#pragma unroll
      for (int d = 1; d < 64; d <<= 1) sum += __shfl_xor(sum, d);
      float wv = e / sum;
      w_s[tid] = wv;
      if (p == 0) outattn[(long)(b * 64 + t) * 64 + tid] = wv;
    }
    __syncthreads();

    // ---- P2c: gi slice = sum_s w_s * ep[s,col] + gix[row,col] ----
    if (tid < 192) {
      const int part = tid >> 6, jj = tid & 63;
      const int col = part * 512 + p * 64 + jj;
      const float* er = ep + (long)(b * 64) * 1536 + col;
      float acc = 0.f;
#pragma unroll 8
      for (int s2 = 0; s2 < 64; ++s2) acc += w_s[s2] * er[(long)s2 * 1536];
      gi_s[tid] = acc + gix[(long)(b * 64 + t) * 1536 + col];
    }
    __syncthreads();

    // ---- P2d: GRU gates + hidden update + publish ----
    if (tid < 64) {
      float rr = fast_sigmoid(gi_s[tid] + gh_s[tid]);
      float zz = fast_sigmoid(gi_s[64 + tid] + gh_s[64 + tid]);
      float nn = fast_tanh(gi_s[128 + tid] + rr * gh_s[128 + tid]);
      float hp = h_loc[tid];
      float hn = (1.f - zz) * nn + zz * hp;
      h_loc[tid] = hn;
      const int j = p * 64 + tid;
      histb[(long)(b * 64 + t) * 512 + j] = (bf16)hn;   // ordinary: next kernel
      if (t == 63) outhT[b * 512 + j] = hn;
      float hn1 = __shfl_xor(hn, 1);  // neighbor's value for packing
      if ((tid & 1) == 0) {
        union { bf16 h[2]; unsigned u; } cv;
        cv.h[0] = (bf16)hn; cv.h[1] = (bf16)hn1;
        unsigned* h32v = (unsigned*)h_bfg;
        __hip_atomic_store(&h32v[b * 256 + (j >> 1)], cv.u, __ATOMIC_RELAXED,
                           __HIP_MEMORY_SCOPE_AGENT);
      }
    }
    ++epoch;
    gbar(bar, g, epoch);
  }
}

// ---------------- in-place log-softmax over V=32000 per row ----------------
__global__ __launch_bounds__(256) void logsm_k(float* __restrict__ C) {
  const long row = blockIdx.x;
  float* x = C + row * 32000L;
  const int tid = threadIdx.x;
  __shared__ float red[4];
  float s = 0.f;
  for (long i = (long)tid * 4; i < 32000; i += 1024) {
    float4 v = *(const float4*)(x + i);
    s += __expf(v.x);
    s += __expf(v.y);
    s += __expf(v.z);
    s += __expf(v.w);
  }
#pragma unroll
  for (int d = 1; d < 64; d <<= 1) s += __shfl_xor(s, d);
  if ((tid & 63) == 0) red[tid >> 6] = s;
  __syncthreads();
  const float lse = __logf(red[0] + red[1] + red[2] + red[3]);
  for (long i = (long)tid * 4; i < 32000; i += 1024) {
    float4 v = *(const float4*)(x + i);
    v.x -= lse; v.y -= lse; v.z -= lse; v.w -= lse;
    *(float4*)(x + i) = v;
  }
}

// ---------------- launcher ----------------
extern "C" void kernel_launch(void* const* d_in, const int* in_sizes, int n_in,
                              void* d_out, int out_size, void* d_ws, size_t ws_size,
                              hipStream_t stream) {
  const float* enc  = (const float*)d_in[0];   // [32,64,512]
  const float* ehid = (const float*)d_in[1];   // [1,32,512]
  const int* tgt    = (const int*)d_in[2];     // [32,64]
  const float* emb  = (const float*)d_in[3];   // [32000,512]
  const float* Wa   = (const float*)d_in[4];   // [512,512]
  const float* ba   = (const float*)d_in[5];   // [512]
  const float* Ua   = (const float*)d_in[6];   // [512,512]
  const float* bu   = (const float*)d_in[7];   // [512]
  const float* Va   = (const float*)d_in[8];   // [1,512]
  // d_in[9] = bv: softmax shift-invariant, unused
  const float* Wih  = (const float*)d_in[10];  // [1536,1024]
  const float* bih  = (const float*)d_in[11];  // [1536]
  const float* Whh  = (const float*)d_in[12];  // [1536,512]
  const float* bhh  = (const float*)d_in[13];  // [1536]
  const float* Wout = (const float*)d_in[14];  // [32000,512]
  const float* bout = (const float*)d_in[15];  // [32000]

  char* ws = (char*)d_ws;
  size_t off = 0;
  auto alloc = [&](size_t bytes) {
    void* pp = ws + off;
    off += (bytes + 255) & ~(size_t)255;
    return pp;
  };
  unsigned* bar  = (unsigned*)alloc(1024);
  unsigned long long* h_bfg = (unsigned long long*)alloc((long)32 * 128 * 8);
  bf16* enc_bf   = (bf16*)alloc((long)2048 * 512 * 2);
  bf16* Wc_bf    = (bf16*)alloc((long)2048 * 512 * 2);    // [Wa;W_hh]
  bf16* Ua_bf    = (bf16*)alloc((long)512 * 512 * 2);
  bf16* Wihx_bf  = (bf16*)alloc((long)1536 * 512 * 2);
  bf16* Wihc_bf  = (bf16*)alloc((long)1536 * 512 * 2);
  bf16* xemb_bf  = (bf16*)alloc((long)2048 * 512 * 2);
  bf16* histb    = (bf16*)alloc((long)2048 * 512 * 2);
  bf16* Wout_bf  = (bf16*)alloc((long)32000 * 512 * 2);
  float* kp      = (float*)alloc((long)2048 * 512 * 4);
  float* kpT     = (float*)alloc((long)32 * 512 * 64 * 4);
  float* gix     = (float*)alloc((long)2048 * 1536 * 4);
  float* ep      = (float*)alloc((long)2048 * 1536 * 4);
  float* QG      = (float*)alloc((long)32 * 2048 * 4);
  (void)ws_size; (void)in_sizes; (void)n_in; (void)out_size;

  float* out0   = (float*)d_out;              // [32,64,32000] log-probs
  float* outhT  = out0 + (long)2048 * 32000;  // [1,32,512]
  float* outatt = outhT + (long)32 * 512;     // [32,64,64]

  hipMemsetAsync(bar, 0, 1024, stream);

  dim3 blk(256);
  // conversions / packing
  f2bf_k<<<dim3(1024), blk, 0, stream>>>(enc, enc_bf, (long)2048 * 512);
  f2bf_k<<<dim3(256), blk, 0, stream>>>(Ua, Ua_bf, (long)512 * 512);
  f2bf_k<<<dim3(16000), blk, 0, stream>>>(Wout, Wout_bf, (long)32000 * 512);
  f2bf_k<<<dim3(256), blk, 0, stream>>>(Wa, Wc_bf, (long)512 * 512);
  f2bf_k<<<dim3(768), blk, 0, stream>>>(Whh, Wc_bf + (long)512 * 512, (long)1536 * 512);
  split_wih_k<<<dim3(768), blk, 0, stream>>>(Wih, Wihx_bf, Wihc_bf);
  embed_k<<<dim3(1024), blk, 0, stream>>>(tgt, emb, xemb_bf);

  // step-invariant GEMMs
  gemm_bt<<<dim3(16 * 4), blk, 0, stream>>>(enc_bf, Ua_bf, bu, kp, 512);         // keys_proj
  kpt_k<<<dim3(4096), blk, 0, stream>>>(kp, kpT);
  gemm_bt<<<dim3(16 * 12), blk, 0, stream>>>(xemb_bf, Wihx_bf, bih, gix, 1536);  // gi_x (+b_ih)
  gemm_bt<<<dim3(16 * 12), blk, 0, stream>>>(enc_bf, Wihc_bf, (const float*)nullptr, ep, 1536);

  // sequential decode (persistent, lightweight barriers)
  recurrence_k<<<dim3(NB_REC), blk, 0, stream>>>(Wc_bf, ba, bhh, ehid, h_bfg, histb,
                                                 QG, kpT, Va, gix, ep, outhT, outatt, bar);

  // logits = h_hist @ Wout^T + bout, then in-place log-softmax
  gemm_bt<<<dim3(16 * 250), blk, 0, stream>>>(histb, Wout_bf, bout, out0, 32000);
  logsm_k<<<dim3(2048), blk, 0, stream>>>(out0);
}